// Round 1
// baseline (67.977 us; speedup 1.0000x reference)
//
#include <hip/hip_runtime.h>
#include <math.h>

#define N_EMB  512
#define N_ELEM (16 * 128 * 128)   // 262144 elements, C==1 so layout is identity

// Kernel 1: one block of 512 threads. Bitonic-sort the 512 codebook scalars
// in LDS, write sorted array to workspace, and zero the loss accumulator
// (d_out is re-poisoned to 0xAA before every timed launch).
__global__ __launch_bounds__(512) void sort_codebook(const float* __restrict__ emb,
                                                     float* __restrict__ ws_sorted,
                                                     float* __restrict__ loss_out) {
    __shared__ float s[N_EMB];
    const int tid = threadIdx.x;
    s[tid] = emb[tid];           // EMBED_DIM == 1 -> flat 512 floats
    __syncthreads();
    for (int k = 2; k <= N_EMB; k <<= 1) {
        for (int j = k >> 1; j > 0; j >>= 1) {
            const int ixj = tid ^ j;
            if (ixj > tid) {
                const float a = s[tid];
                const float b = s[ixj];
                const bool asc = ((tid & k) == 0);
                if ((a > b) == asc) { s[tid] = b; s[ixj] = a; }
            }
            __syncthreads();
        }
    }
    ws_sorted[tid] = s[tid];
    if (tid == 0) *loss_out = 0.0f;
}

// Kernel 2: 256 blocks x 256 threads, 4 elements/thread (float4 coalesced).
// Branchless binary search over the sorted codebook in LDS (9 steps), then
// compare the two bracketing candidates by squared distance (matches the
// reference's argmin over (x-e)^2 up to measure-zero midpoint ties).
__global__ __launch_bounds__(256) void vq_nearest(const float* __restrict__ x,
                                                  const float* __restrict__ sorted,
                                                  float* __restrict__ out,
                                                  float* __restrict__ loss_out) {
    __shared__ float s[N_EMB + 1];
    const int tid = threadIdx.x;
    s[tid]       = sorted[tid];
    s[tid + 256] = sorted[tid + 256];
    if (tid == 0) s[N_EMB] = INFINITY;   // sentinel so pos==511 picks s[511]
    __syncthreads();

    const int gid = blockIdx.x * 256 + tid;
    const float4 xv = reinterpret_cast<const float4*>(x)[gid];
    float xs[4] = {xv.x, xv.y, xv.z, xv.w};
    float q[4];
    float acc = 0.0f;

    #pragma unroll
    for (int e = 0; e < 4; ++e) {
        const float xx = xs[e];
        // largest pos with s[pos] <= xx (pos stays 0 if xx < s[0])
        int pos = 0;
        #pragma unroll
        for (int step = 256; step > 0; step >>= 1) {
            const int cand = pos + step;        // cand <= 511 always
            if (xx >= s[cand]) pos = cand;
        }
        const float c0 = s[pos];
        const float c1 = s[pos + 1];
        const float d0 = xx - c0;               // may be negative if xx < s[0]; squared fixes it
        const float d1 = c1 - xx;               // INF at the top edge -> never chosen
        const float d0s = d0 * d0;
        const float d1s = d1 * d1;
        const bool take0 = (d0s <= d1s);
        q[e] = take0 ? c0 : c1;
        acc += take0 ? d0s : d1s;               // (q - x)^2 for the loss
    }

    float4 qv = make_float4(q[0], q[1], q[2], q[3]);
    reinterpret_cast<float4*>(out)[gid] = qv;

    // loss = 1.25 * mean((q-x)^2): wave shuffle-reduce, then block LDS reduce,
    // then one scaled atomicAdd per block.
    #pragma unroll
    for (int off = 32; off > 0; off >>= 1)
        acc += __shfl_down(acc, off, 64);

    __shared__ float wsum[4];
    const int wave = tid >> 6;
    const int lane = tid & 63;
    if (lane == 0) wsum[wave] = acc;
    __syncthreads();
    if (tid == 0) {
        const float bsum = wsum[0] + wsum[1] + wsum[2] + wsum[3];
        atomicAdd(loss_out, bsum * (1.25f / (float)N_ELEM));
    }
}

extern "C" void kernel_launch(void* const* d_in, const int* in_sizes, int n_in,
                              void* d_out, int out_size, void* d_ws, size_t ws_size,
                              hipStream_t stream) {
    const float* x   = (const float*)d_in[0];   // pre_quantized (16,1,128,128)
    const float* emb = (const float*)d_in[1];   // emb_weight (512,1)
    float* out  = (float*)d_out;                // [0..N_ELEM): quantized, [N_ELEM]: loss
    float* srt  = (float*)d_ws;                 // 512 floats of scratch
    float* loss = out + N_ELEM;

    sort_codebook<<<1, 512, 0, stream>>>(emb, srt, loss);
    vq_nearest<<<256, 256, 0, stream>>>(x, srt, out, loss);
}

// Round 2
// 65.550 us; speedup vs baseline: 1.0370x; 1.0370x over previous
//
#include <hip/hip_runtime.h>
#include <math.h>

#define N_EMB  512
#define N_ELEM (16 * 128 * 128)   // 262144, C==1 so NCHW<->NHWC is identity
#define NBLK   128                // 512 thr, 4 elem/thr -> 128*512*4 = N_ELEM

// Kernel 1: each block sorts the 512-entry codebook in its own LDS (bitonic,
// 512 threads — redundant across blocks but parallel, and it removes the
// separate sort kernel + its launch dependency). Then branchless binary
// search (9 LDS steps) per element, float4 coalesced I/O, and ONE non-atomic
// partial-loss store per block (kills the 256 contended same-address atomics
// that I believe dominated the 68 us).
__global__ __launch_bounds__(512) void vq_kernel(const float* __restrict__ x,
                                                 const float* __restrict__ emb,
                                                 float* __restrict__ out,
                                                 float* __restrict__ partials) {
    __shared__ float s[N_EMB + 1];
    const int tid = threadIdx.x;
    s[tid] = emb[tid];                 // EMBED_DIM == 1 -> flat 512 floats
    if (tid == 0) s[N_EMB] = INFINITY; // sentinel: pos==511 never picks c1
    __syncthreads();
    for (int k = 2; k <= N_EMB; k <<= 1) {
        for (int j = k >> 1; j > 0; j >>= 1) {
            const int ixj = tid ^ j;
            if (ixj > tid) {
                const float a = s[tid];
                const float b = s[ixj];
                if ((a > b) == ((tid & k) == 0)) { s[tid] = b; s[ixj] = a; }
            }
            __syncthreads();
        }
    }

    const int gid = blockIdx.x * 512 + tid;
    const float4 xv = reinterpret_cast<const float4*>(x)[gid];
    const float xs[4] = {xv.x, xv.y, xv.z, xv.w};
    float q[4];
    float acc = 0.0f;

    #pragma unroll
    for (int e = 0; e < 4; ++e) {
        const float xx = xs[e];
        int pos = 0;                    // largest pos with s[pos] <= xx
        #pragma unroll
        for (int step = 256; step > 0; step >>= 1) {
            if (xx >= s[pos + step]) pos += step;   // pos+step <= 511 always
        }
        const float c0 = s[pos];
        const float c1 = s[pos + 1];    // INF sentinel at top edge
        const float d0 = xx - c0;       // negative iff xx < s[0]; square fixes
        const float d1 = c1 - xx;
        const float d0s = d0 * d0;
        const float d1s = d1 * d1;
        const bool t0 = (d0s <= d1s);
        q[e] = t0 ? c0 : c1;
        acc += t0 ? d0s : d1s;          // (q - x)^2 for the loss
    }
    reinterpret_cast<float4*>(out)[gid] = make_float4(q[0], q[1], q[2], q[3]);

    // block-level loss partial: wave shuffle reduce -> LDS across 8 waves ->
    // one plain store per block (no atomics anywhere).
    #pragma unroll
    for (int off = 32; off > 0; off >>= 1)
        acc += __shfl_down(acc, off, 64);
    __shared__ float wsum[8];
    if ((tid & 63) == 0) wsum[tid >> 6] = acc;
    __syncthreads();
    if (tid == 0) {
        float b = 0.0f;
        #pragma unroll
        for (int w = 0; w < 8; ++w) b += wsum[w];
        partials[blockIdx.x] = b;
    }
}

// Kernel 2: one tiny block sums the 128 partials and writes the loss scalar
// directly (overwrite, so no zero-init of the poisoned d_out slot needed).
__global__ __launch_bounds__(128) void loss_reduce(const float* __restrict__ partials,
                                                   float* __restrict__ loss_out) {
    float v = partials[threadIdx.x];
    #pragma unroll
    for (int off = 32; off > 0; off >>= 1)
        v += __shfl_down(v, off, 64);
    __shared__ float w2[2];
    if ((threadIdx.x & 63) == 0) w2[threadIdx.x >> 6] = v;
    __syncthreads();
    if (threadIdx.x == 0)
        *loss_out = (w2[0] + w2[1]) * (1.25f / (float)N_ELEM);
}

extern "C" void kernel_launch(void* const* d_in, const int* in_sizes, int n_in,
                              void* d_out, int out_size, void* d_ws, size_t ws_size,
                              hipStream_t stream) {
    const float* x   = (const float*)d_in[0];   // pre_quantized (16,1,128,128)
    const float* emb = (const float*)d_in[1];   // emb_weight (512,1)
    float* out      = (float*)d_out;            // [0..N_ELEM): quantized
    float* loss     = out + N_ELEM;             // [N_ELEM]: scalar loss
    float* partials = (float*)d_ws;             // 128 floats scratch

    vq_kernel<<<NBLK, 512, 0, stream>>>(x, emb, out, partials);
    loss_reduce<<<1, 128, 0, stream>>>(partials, loss);
}